// Round 1
// baseline (454.935 us; speedup 1.0000x reference)
//
#include <hip/hip_runtime.h>

#define N_NODES 50000
#define N_EDGES 800000
#define D_IN 256
#define D_OUT 64
#define NEG_SLOPE 0.01f

// ---------------- Kernel 1: h = X*W + b, and a1/a2 per-node scalars ----------
// One wave (64 lanes) per node row; lane j computes h[row][j].
__global__ __launch_bounds__(256) void k_gemm(
    const float* __restrict__ feat, const float* __restrict__ W,
    const float* __restrict__ bias,
    const float* __restrict__ a1w, const float* __restrict__ a1b,
    const float* __restrict__ a2w, const float* __restrict__ a2b,
    float* __restrict__ h, float* __restrict__ a1, float* __restrict__ a2) {
  int gt = blockIdx.x * blockDim.x + threadIdx.x;
  int row = gt >> 6;
  int lane = gt & 63;
  if (row >= N_NODES) return;

  const float4* f4 = reinterpret_cast<const float4*>(feat + (size_t)row * D_IN);
  float acc = 0.f;
#pragma unroll 8
  for (int k4 = 0; k4 < D_IN / 4; ++k4) {
    float4 v = f4[k4];
    int k = k4 * 4;
    acc += v.x * W[(k + 0) * D_OUT + lane];
    acc += v.y * W[(k + 1) * D_OUT + lane];
    acc += v.z * W[(k + 2) * D_OUT + lane];
    acc += v.w * W[(k + 3) * D_OUT + lane];
  }
  acc += bias[lane];
  h[(size_t)row * D_OUT + lane] = acc;

  // wave-reduce h . a1_w and h . a2_w
  float s1 = acc * a1w[lane];
  float s2 = acc * a2w[lane];
#pragma unroll
  for (int off = 32; off > 0; off >>= 1) {
    s1 += __shfl_xor(s1, off);
    s2 += __shfl_xor(s2, off);
  }
  if (lane == 0) {
    a1[row] = s1 + a1b[0];
    a2[row] = s2 + a2b[0];
  }
}

// Monotone float->uint encoding so atomicMax(uint) orders like float.
__device__ __forceinline__ unsigned enc_f32(float f) {
  unsigned u = __float_as_uint(f);
  return (u & 0x80000000u) ? ~u : (u | 0x80000000u);
}
__device__ __forceinline__ float dec_f32(unsigned u) {
  return (u & 0x80000000u) ? __uint_as_float(u ^ 0x80000000u)
                           : __uint_as_float(~u);
}

// ---------------- Kernel 2: per-edge score + segment max ----------
__global__ __launch_bounds__(256) void k_score_max(
    const int* __restrict__ rows, const int* __restrict__ cols,
    const float* __restrict__ a1, const float* __restrict__ a2,
    unsigned* __restrict__ rmax) {
  int e = blockIdx.x * blockDim.x + threadIdx.x;
  if (e >= N_EDGES) return;
  int r = rows[e], c = cols[e];
  float s = a1[r] + a2[c];
  s = (s > 0.f) ? s : NEG_SLOPE * s;
  atomicMax(&rmax[r], enc_f32(s));
}

// ---------------- Kernel 3: ex = exp(score - rowmax), segment sum ----------
__global__ __launch_bounds__(256) void k_exp_sum(
    const int* __restrict__ rows, const int* __restrict__ cols,
    const float* __restrict__ a1, const float* __restrict__ a2,
    const unsigned* __restrict__ rmax,
    float* __restrict__ ex, float* __restrict__ denom) {
  int e = blockIdx.x * blockDim.x + threadIdx.x;
  if (e >= N_EDGES) return;
  int r = rows[e], c = cols[e];
  float s = a1[r] + a2[c];
  s = (s > 0.f) ? s : NEG_SLOPE * s;
  float m = dec_f32(rmax[r]);
  float v = __expf(s - m);
  ex[e] = v;
  atomicAdd(&denom[r], v);
}

// ---------------- Kernel 4: out[r] += (ex/denom[r]) * h[c] ----------
// One wave per edge, lane = output dim. Coalesced h read and out atomics.
__global__ __launch_bounds__(256) void k_aggregate(
    const int* __restrict__ rows, const int* __restrict__ cols,
    const float* __restrict__ ex, const float* __restrict__ denom,
    const float* __restrict__ h, float* __restrict__ out) {
  long long gt = (long long)blockIdx.x * blockDim.x + threadIdx.x;
  int e = (int)(gt >> 6);
  int lane = (int)(gt & 63);
  if (e >= N_EDGES) return;
  int r = rows[e], c = cols[e];
  float att = ex[e] / denom[r];
  atomicAdd(&out[(size_t)r * D_OUT + lane], att * h[(size_t)c * D_OUT + lane]);
}

extern "C" void kernel_launch(void* const* d_in, const int* in_sizes, int n_in,
                              void* d_out, int out_size, void* d_ws, size_t ws_size,
                              hipStream_t stream) {
  const float* feat = (const float*)d_in[0];
  const int* eidx   = (const int*)d_in[1];   // [2, E] int32 (JAX x64 disabled)
  // d_in[2] edge_values: unused by reference output
  const float* W    = (const float*)d_in[3];
  const float* bias = (const float*)d_in[4];
  const float* a1w  = (const float*)d_in[5];
  const float* a1b  = (const float*)d_in[6];
  const float* a2w  = (const float*)d_in[7];
  const float* a2b  = (const float*)d_in[8];
  // a3_w, a3_b unused
  float* out = (float*)d_out;

  const int* rows = eidx;
  const int* cols = eidx + N_EDGES;

  // workspace layout
  char* ws = (char*)d_ws;
  float*    h     = (float*)ws;                       // N*64 f32 = 12.8 MB
  float*    a1    = (float*)(ws + 12800000);          // 200 KB
  float*    a2    = (float*)(ws + 13000000);          // 200 KB
  unsigned* rmax  = (unsigned*)(ws + 13200000);       // 200 KB
  float*    denom = (float*)(ws + 13400000);          // 200 KB
  float*    ex    = (float*)(ws + 13600000);          // 3.2 MB -> total 16.8 MB

  // init: rmax=0 encodes "below -inf"; denom=0; out=0
  hipMemsetAsync(rmax, 0, N_NODES * sizeof(unsigned), stream);
  hipMemsetAsync(denom, 0, N_NODES * sizeof(float), stream);
  hipMemsetAsync(out, 0, (size_t)N_NODES * D_OUT * sizeof(float), stream);

  {
    int threads = N_NODES * 64;
    int blocks = (threads + 255) / 256;
    k_gemm<<<blocks, 256, 0, stream>>>(feat, W, bias, a1w, a1b, a2w, a2b, h, a1, a2);
  }
  {
    int blocks = (N_EDGES + 255) / 256;
    k_score_max<<<blocks, 256, 0, stream>>>(rows, cols, a1, a2, rmax);
    k_exp_sum<<<blocks, 256, 0, stream>>>(rows, cols, a1, a2, rmax, ex, denom);
  }
  {
    long long threads = (long long)N_EDGES * 64;
    int blocks = (int)((threads + 255) / 256);
    k_aggregate<<<blocks, 256, 0, stream>>>(rows, cols, ex, denom, h, out);
  }
}